// Round 3
// baseline (1708.461 us; speedup 1.0000x reference)
//
#include <hip/hip_runtime.h>
#include <hip/hip_cooperative_groups.h>
#include <math.h>

namespace cg = cooperative_groups;

#define D 512
#define STEPS 6
#define MAXB1 1024

// ws layout (floats): hbuf[1024] | c[512] | ctx[512] | ctxs[3072] | logits[512]
//                     | pm[1024] | ps[1024] | pv[1024*512]
#define WS_HBUF   0
#define WS_C      1024
#define WS_CTX    1536
#define WS_CTXS   2048
#define WS_LOGITS 5120
#define WS_PM     5632
#define WS_PS     6656
#define WS_PV     7680

__device__ __forceinline__ float wave_reduce_sum(float v) {
#pragma unroll
    for (int off = 32; off > 0; off >>= 1) v += __shfl_xor(v, off);
    return v;
}

__device__ __forceinline__ float dot8(const float4& a, const float4& b,
                                      const float4& ha, const float4& hb) {
    return a.x*ha.x + a.y*ha.y + a.z*ha.z + a.w*ha.w
         + b.x*hb.x + b.y*hb.y + b.z*hb.z + b.w*hb.w;
}

#define ONLINE(dv, av, bv) do {                                          \
    if ((dv) > m) {                                                      \
        float sc_ = __expf(m - (dv));                                    \
        s *= sc_;                                                        \
        va.x *= sc_; va.y *= sc_; va.z *= sc_; va.w *= sc_;              \
        vb.x *= sc_; vb.y *= sc_; vb.z *= sc_; vb.w *= sc_;              \
        m = (dv);                                                        \
    }                                                                    \
    float w_ = __expf((dv) - m);                                         \
    s += w_;                                                             \
    va.x += w_*(av).x; va.y += w_*(av).y; va.z += w_*(av).z; va.w += w_*(av).w; \
    vb.x += w_*(bv).x; vb.y += w_*(bv).y; vb.z += w_*(bv).z; vb.w += w_*(bv).w; \
} while (0)

// ======================= fallback kernels (round-1, proven) =======================

__global__ __launch_bounds__(256, 4) void attn_kernel(
    const float* __restrict__ x, const float* __restrict__ h,
    float* __restrict__ pm, float* __restrict__ ps, float* __restrict__ pv, int N)
{
    __shared__ float h_s[D];
    __shared__ float red_v[4][D];
    __shared__ float red_ms[8];
    for (int i = threadIdx.x; i < D; i += 256) h_s[i] = h[i];
    __syncthreads();

    const int wave = threadIdx.x >> 6, lane = threadIdx.x & 63;
    const int nw = gridDim.x << 2;
    const float4 ha = ((const float4*)h_s)[lane];
    const float4 hb = ((const float4*)h_s)[64 + lane];

    float m = -1e30f, s = 0.f;
    float4 va = make_float4(0.f, 0.f, 0.f, 0.f);
    float4 vb = make_float4(0.f, 0.f, 0.f, 0.f);

    int i = (blockIdx.x << 2) + wave;
    const int limit4 = N - 3 * nw;
    for (; i < limit4; i += (nw << 2)) {
        const float4* x0 = (const float4*)(x + (size_t)i * D);
        const float4* x1 = (const float4*)(x + (size_t)(i + nw) * D);
        const float4* x2 = (const float4*)(x + (size_t)(i + 2 * nw) * D);
        const float4* x3 = (const float4*)(x + (size_t)(i + 3 * nw) * D);
        float4 a0 = x0[lane], b0 = x0[64 + lane];
        float4 a1 = x1[lane], b1 = x1[64 + lane];
        float4 a2 = x2[lane], b2 = x2[64 + lane];
        float4 a3 = x3[lane], b3 = x3[64 + lane];
        float d0 = dot8(a0, b0, ha, hb);
        float d1 = dot8(a1, b1, ha, hb);
        float d2 = dot8(a2, b2, ha, hb);
        float d3 = dot8(a3, b3, ha, hb);
#pragma unroll
        for (int off = 32; off > 0; off >>= 1) {
            d0 += __shfl_xor(d0, off);
            d1 += __shfl_xor(d1, off);
            d2 += __shfl_xor(d2, off);
            d3 += __shfl_xor(d3, off);
        }
        ONLINE(d0, a0, b0);
        ONLINE(d1, a1, b1);
        ONLINE(d2, a2, b2);
        ONLINE(d3, a3, b3);
    }
    for (; i < N; i += nw) {
        const float4* x0 = (const float4*)(x + (size_t)i * D);
        float4 a0 = x0[lane], b0 = x0[64 + lane];
        float d0 = dot8(a0, b0, ha, hb);
        d0 = wave_reduce_sum(d0);
        ONLINE(d0, a0, b0);
    }

    ((float4*)red_v[wave])[lane] = va;
    ((float4*)red_v[wave])[64 + lane] = vb;
    if (lane == 0) { red_ms[wave] = m; red_ms[4 + wave] = s; }
    __syncthreads();

    float m0 = red_ms[0], m1 = red_ms[1], m2 = red_ms[2], m3 = red_ms[3];
    float bm = fmaxf(fmaxf(m0, m1), fmaxf(m2, m3));
    float sc0 = __expf(m0 - bm), sc1 = __expf(m1 - bm);
    float sc2 = __expf(m2 - bm), sc3 = __expf(m3 - bm);
    if (threadIdx.x == 0) {
        pm[blockIdx.x] = bm;
        ps[blockIdx.x] = red_ms[4]*sc0 + red_ms[5]*sc1 + red_ms[6]*sc2 + red_ms[7]*sc3;
    }
    const int t = threadIdx.x;
    float v0 = red_v[0][t]*sc0 + red_v[1][t]*sc1 + red_v[2][t]*sc2 + red_v[3][t]*sc3;
    float v1 = red_v[0][t+256]*sc0 + red_v[1][t+256]*sc1
             + red_v[2][t+256]*sc2 + red_v[3][t+256]*sc3;
    pv[(size_t)blockIdx.x * D + t] = v0;
    pv[(size_t)blockIdx.x * D + t + 256] = v1;
}

__global__ __launch_bounds__(256) void combine_kernel(
    const float* __restrict__ pm, const float* __restrict__ ps,
    const float* __restrict__ pv, float* __restrict__ ctx,
    float* __restrict__ ctx_store, int B1)
{
    __shared__ float sm[MAXB1];
    __shared__ float red[8];
    __shared__ float pr[4][64];
    const int tid = threadIdx.x, lane = tid & 63, wave = tid >> 6;

    float lm = -1e30f;
    for (int b = tid; b < B1; b += 256) lm = fmaxf(lm, pm[b]);
#pragma unroll
    for (int off = 32; off > 0; off >>= 1) lm = fmaxf(lm, __shfl_xor(lm, off));
    if (lane == 0) red[wave] = lm;
    __syncthreads();
    float M = fmaxf(fmaxf(red[0], red[1]), fmaxf(red[2], red[3]));

    float lS = 0.f;
    for (int b = tid; b < B1; b += 256) {
        float e = __expf(pm[b] - M);
        sm[b] = e;
        lS += ps[b] * e;
    }
#pragma unroll
    for (int off = 32; off > 0; off >>= 1) lS += __shfl_xor(lS, off);
    if (lane == 0) red[4 + wave] = lS;
    __syncthreads();
    float S = red[4] + red[5] + red[6] + red[7];

    const int d = (blockIdx.x << 6) + lane;
    float acc = 0.f;
    for (int b = wave; b < B1; b += 4)
        acc += pv[(size_t)b * D + d] * sm[b];
    pr[wave][lane] = acc;
    __syncthreads();
    if (tid < 64) {
        float v = (pr[0][lane] + pr[1][lane] + pr[2][lane] + pr[3][lane]) / S;
        int dd = (blockIdx.x << 6) + lane;
        ctx[dd] = v;
        ctx_store[dd] = v;
    }
}

__global__ __launch_bounds__(256) void lstm_kernel(
    const float* __restrict__ W_ih, const float* __restrict__ W_hh,
    const float* __restrict__ b_ih, const float* __restrict__ b_hh,
    const float* __restrict__ ctx, const float* __restrict__ h_in,
    float* __restrict__ h_out, float* __restrict__ c)
{
    __shared__ float inp[2 * D];
    __shared__ float gate[4];
    const int tid = threadIdx.x, lane = tid & 63, g = tid >> 6;
    const int j = blockIdx.x;
    for (int i = tid; i < D; i += 256) { inp[i] = ctx[i]; inp[D + i] = h_in[i]; }
    __syncthreads();

    const int row = (g << 9) + j;
    const float4* wr = (const float4*)(W_ih + (size_t)row * (2 * D));
    float dot = 0.f;
#pragma unroll
    for (int q = 0; q < 4; ++q) {
        float4 w4 = wr[lane + (q << 6)];
        float4 i4 = ((const float4*)inp)[lane + (q << 6)];
        dot += w4.x*i4.x + w4.y*i4.y + w4.z*i4.z + w4.w*i4.w;
    }
    const float4* wr2 = (const float4*)(W_hh + (size_t)row * D);
#pragma unroll
    for (int q = 0; q < 2; ++q) {
        float4 w4 = wr2[lane + (q << 6)];
        float4 i4 = ((const float4*)(inp + D))[lane + (q << 6)];
        dot += w4.x*i4.x + w4.y*i4.y + w4.z*i4.z + w4.w*i4.w;
    }
    dot = wave_reduce_sum(dot);
    if (lane == 0) gate[g] = dot + b_ih[row] + b_hh[row];
    __syncthreads();
    if (tid == 0) {
        float ig = 1.f / (1.f + __expf(-gate[0]));
        float fg = 1.f / (1.f + __expf(-gate[1]));
        float gg = tanhf(gate[2]);
        float og = 1.f / (1.f + __expf(-gate[3]));
        float cn = fg * c[j] + ig * gg;
        c[j] = cn;
        h_out[j] = og * tanhf(cn);
    }
}

__global__ __launch_bounds__(256) void proj_kernel(
    const float* __restrict__ W_proj, const float* __restrict__ b_proj,
    const float* __restrict__ ctxs, float* __restrict__ logits)
{
    __shared__ float cc[STEPS * D];
    const int tid = threadIdx.x, lane = tid & 63, g = tid >> 6;
    for (int i = tid; i < STEPS * D; i += 256) cc[i] = ctxs[i];
    __syncthreads();

    const int row = (blockIdx.x << 2) + g;
    const float4* wr = (const float4*)(W_proj + (size_t)row * (STEPS * D));
    float dot = 0.f;
#pragma unroll
    for (int q = 0; q < 12; ++q) {
        float4 w4 = wr[lane + (q << 6)];
        float4 i4 = ((const float4*)cc)[lane + (q << 6)];
        dot += w4.x*i4.x + w4.y*i4.y + w4.z*i4.z + w4.w*i4.w;
    }
    dot = wave_reduce_sum(dot);
    if (lane == 0) logits[row] = dot + b_proj[row];
}

__global__ void softmax512_kernel(const float* __restrict__ logits, float* __restrict__ out)
{
    __shared__ float red[8];
    const int tid = threadIdx.x, lane = tid & 63, wave = tid >> 6;
    float v = logits[tid];
    float m = v;
#pragma unroll
    for (int off = 32; off > 0; off >>= 1) m = fmaxf(m, __shfl_xor(m, off));
    if (lane == 0) red[wave] = m;
    __syncthreads();
    m = red[0];
#pragma unroll
    for (int k = 1; k < 8; ++k) m = fmaxf(m, red[k]);
    __syncthreads();
    float e = __expf(v - m);
    float s = e;
#pragma unroll
    for (int off = 32; off > 0; off >>= 1) s += __shfl_xor(s, off);
    if (lane == 0) red[wave] = s;
    __syncthreads();
    s = 0.f;
#pragma unroll
    for (int k = 0; k < 8; ++k) s += red[k];
    out[tid] = e / s;
}

// ======================= fused cooperative kernel (grid-size-agnostic) =======================

struct SharedU {
    union {
        struct { float h_s[D]; float red_v[4][D]; float red_ms[8]; } attn;
        struct { float sm[512]; float red[8]; float pr[4][64]; } comb;
        struct { float inp[2 * D]; float gate[4]; } lstm;
        struct { float cc[STEPS * D]; } proj;
    };
};

__global__ __launch_bounds__(256, 2) void s2s_kernel(
    const float* __restrict__ x,
    const float* __restrict__ W_ih, const float* __restrict__ W_hh,
    const float* __restrict__ b_ih, const float* __restrict__ b_hh,
    const float* __restrict__ W_proj, const float* __restrict__ b_proj,
    float* __restrict__ out, float* __restrict__ ws, int N)
{
    cg::grid_group grid = cg::this_grid();
    __shared__ SharedU su;

    float* hbuf   = ws + WS_HBUF;
    float* c      = ws + WS_C;
    float* ctx    = ws + WS_CTX;
    float* ctxs   = ws + WS_CTXS;
    float* logits = ws + WS_LOGITS;
    float* pm     = ws + WS_PM;
    float* ps     = ws + WS_PS;
    float* pv     = ws + WS_PV;

    const int tid = threadIdx.x, lane = tid & 63, wave = tid >> 6;
    const int bid = blockIdx.x;
    const int NB = gridDim.x;          // <= 512
    const int nw = NB << 2;

    if (bid == 0)
        for (int i = tid; i < 1536; i += 256) ws[i] = 0.f;   // h (both bufs), c
    grid.sync();

    for (int t = 0; t < STEPS; ++t) {
        float* h_in  = hbuf + ((t & 1) << 9);
        float* h_out = hbuf + (((t + 1) & 1) << 9);

        // ---- phase 1: online-softmax attention partials ----
        {
            for (int i = tid; i < D; i += 256) su.attn.h_s[i] = h_in[i];
            __syncthreads();
            const float4 ha = ((const float4*)su.attn.h_s)[lane];
            const float4 hb = ((const float4*)su.attn.h_s)[64 + lane];

            float m = -1e30f, s = 0.f;
            float4 va = make_float4(0.f, 0.f, 0.f, 0.f);
            float4 vb = make_float4(0.f, 0.f, 0.f, 0.f);

            int i = (bid << 2) + wave;
            const int limit4 = N - 3 * nw;
            for (; i < limit4; i += (nw << 2)) {
                const float4* x0 = (const float4*)(x + (size_t)i * D);
                const float4* x1 = (const float4*)(x + (size_t)(i + nw) * D);
                const float4* x2 = (const float4*)(x + (size_t)(i + 2 * nw) * D);
                const float4* x3 = (const float4*)(x + (size_t)(i + 3 * nw) * D);
                float4 a0 = x0[lane], b0 = x0[64 + lane];
                float4 a1 = x1[lane], b1 = x1[64 + lane];
                float4 a2 = x2[lane], b2 = x2[64 + lane];
                float4 a3 = x3[lane], b3 = x3[64 + lane];
                float d0 = dot8(a0, b0, ha, hb);
                float d1 = dot8(a1, b1, ha, hb);
                float d2 = dot8(a2, b2, ha, hb);
                float d3 = dot8(a3, b3, ha, hb);
#pragma unroll
                for (int off = 32; off > 0; off >>= 1) {
                    d0 += __shfl_xor(d0, off);
                    d1 += __shfl_xor(d1, off);
                    d2 += __shfl_xor(d2, off);
                    d3 += __shfl_xor(d3, off);
                }
                ONLINE(d0, a0, b0);
                ONLINE(d1, a1, b1);
                ONLINE(d2, a2, b2);
                ONLINE(d3, a3, b3);
            }
            for (; i < N; i += nw) {
                const float4* x0 = (const float4*)(x + (size_t)i * D);
                float4 a0 = x0[lane], b0 = x0[64 + lane];
                float d0 = dot8(a0, b0, ha, hb);
                d0 = wave_reduce_sum(d0);
                ONLINE(d0, a0, b0);
            }

            ((float4*)su.attn.red_v[wave])[lane] = va;
            ((float4*)su.attn.red_v[wave])[64 + lane] = vb;
            if (lane == 0) { su.attn.red_ms[wave] = m; su.attn.red_ms[4 + wave] = s; }
            __syncthreads();

            float m0 = su.attn.red_ms[0], m1 = su.attn.red_ms[1];
            float m2 = su.attn.red_ms[2], m3 = su.attn.red_ms[3];
            float bm = fmaxf(fmaxf(m0, m1), fmaxf(m2, m3));
            float sc0 = __expf(m0 - bm), sc1 = __expf(m1 - bm);
            float sc2 = __expf(m2 - bm), sc3 = __expf(m3 - bm);
            if (tid == 0) {
                pm[bid] = bm;
                ps[bid] = su.attn.red_ms[4]*sc0 + su.attn.red_ms[5]*sc1
                        + su.attn.red_ms[6]*sc2 + su.attn.red_ms[7]*sc3;
            }
            float v0 = su.attn.red_v[0][tid]*sc0 + su.attn.red_v[1][tid]*sc1
                     + su.attn.red_v[2][tid]*sc2 + su.attn.red_v[3][tid]*sc3;
            float v1 = su.attn.red_v[0][tid+256]*sc0 + su.attn.red_v[1][tid+256]*sc1
                     + su.attn.red_v[2][tid+256]*sc2 + su.attn.red_v[3][tid+256]*sc3;
            pv[(size_t)bid * D + tid] = v0;
            pv[(size_t)bid * D + tid + 256] = v1;
        }
        grid.sync();

        // ---- phase 2: combine NB partials -> ctx ----
        if (bid < 8) {
            float lm = -1e30f;
            for (int b = tid; b < NB; b += 256) lm = fmaxf(lm, pm[b]);
#pragma unroll
            for (int off = 32; off > 0; off >>= 1) lm = fmaxf(lm, __shfl_xor(lm, off));
            if (lane == 0) su.comb.red[wave] = lm;
            __syncthreads();
            float M = fmaxf(fmaxf(su.comb.red[0], su.comb.red[1]),
                            fmaxf(su.comb.red[2], su.comb.red[3]));

            float lS = 0.f;
            for (int b = tid; b < NB; b += 256) {
                float e = __expf(pm[b] - M);
                su.comb.sm[b] = e;
                lS += ps[b] * e;
            }
#pragma unroll
            for (int off = 32; off > 0; off >>= 1) lS += __shfl_xor(lS, off);
            if (lane == 0) su.comb.red[4 + wave] = lS;
            __syncthreads();
            float S = su.comb.red[4] + su.comb.red[5] + su.comb.red[6] + su.comb.red[7];

            const int d = (bid << 6) + lane;
            float acc = 0.f;
            for (int b = wave; b < NB; b += 4)
                acc += pv[(size_t)b * D + d] * su.comb.sm[b];
            su.comb.pr[wave][lane] = acc;
            __syncthreads();
            if (tid < 64) {
                float v = (su.comb.pr[0][lane] + su.comb.pr[1][lane]
                         + su.comb.pr[2][lane] + su.comb.pr[3][lane]) / S;
                ctx[d] = v;
                ctxs[t * D + d] = v;
            }
        }
        grid.sync();

        // ---- phase 3: LSTM cell (virtual block j) ----
        {
            for (int i = tid; i < D; i += 256) {
                su.lstm.inp[i] = ctx[i];
                su.lstm.inp[D + i] = h_in[i];
            }
            __syncthreads();

            for (int j = bid; j < D; j += NB) {
                const int row = (wave << 9) + j;
                const float4* wr = (const float4*)(W_ih + (size_t)row * (2 * D));
                float dot = 0.f;
#pragma unroll
                for (int q = 0; q < 4; ++q) {
                    float4 w4 = wr[lane + (q << 6)];
                    float4 i4 = ((const float4*)su.lstm.inp)[lane + (q << 6)];
                    dot += w4.x*i4.x + w4.y*i4.y + w4.z*i4.z + w4.w*i4.w;
                }
                const float4* wr2 = (const float4*)(W_hh + (size_t)row * D);
#pragma unroll
                for (int q = 0; q < 2; ++q) {
                    float4 w4 = wr2[lane + (q << 6)];
                    float4 i4 = ((const float4*)(su.lstm.inp + D))[lane + (q << 6)];
                    dot += w4.x*i4.x + w4.y*i4.y + w4.z*i4.z + w4.w*i4.w;
                }
                dot = wave_reduce_sum(dot);
                if (lane == 0) su.lstm.gate[wave] = dot + b_ih[row] + b_hh[row];
                __syncthreads();
                if (tid == 0) {
                    float ig = 1.f / (1.f + __expf(-su.lstm.gate[0]));
                    float fg = 1.f / (1.f + __expf(-su.lstm.gate[1]));
                    float gg = tanhf(su.lstm.gate[2]);
                    float og = 1.f / (1.f + __expf(-su.lstm.gate[3]));
                    float cn = fg * c[j] + ig * gg;
                    c[j] = cn;
                    h_out[j] = og * tanhf(cn);
                }
                __syncthreads();   // gate[] reuse safety when NB < 512
            }
        }
        grid.sync();
    }

    // ---- projection ----
    {
        for (int i = tid; i < STEPS * D; i += 256) su.proj.cc[i] = ctxs[i];
        __syncthreads();
        for (int rg = bid; rg < 128; rg += NB) {
            const int row = (rg << 2) + wave;
            const float4* wr = (const float4*)(W_proj + (size_t)row * (STEPS * D));
            float dot = 0.f;
#pragma unroll
            for (int q = 0; q < 12; ++q) {
                float4 w4 = wr[lane + (q << 6)];
                float4 i4 = ((const float4*)su.proj.cc)[lane + (q << 6)];
                dot += w4.x*i4.x + w4.y*i4.y + w4.z*i4.z + w4.w*i4.w;
            }
            dot = wave_reduce_sum(dot);
            if (lane == 0) logits[row] = dot + b_proj[row];
        }
    }
    grid.sync();

    // ---- final softmax (block 0) ----
    if (bid == 0) {
        float v0 = logits[tid], v1 = logits[tid + 256];
        float m = fmaxf(v0, v1);
#pragma unroll
        for (int off = 32; off > 0; off >>= 1) m = fmaxf(m, __shfl_xor(m, off));
        if (lane == 0) su.comb.red[wave] = m;
        __syncthreads();
        m = fmaxf(fmaxf(su.comb.red[0], su.comb.red[1]),
                  fmaxf(su.comb.red[2], su.comb.red[3]));
        __syncthreads();
        float e0 = __expf(v0 - m), e1 = __expf(v1 - m);
        float ls = e0 + e1;
#pragma unroll
        for (int off = 32; off > 0; off >>= 1) ls += __shfl_xor(ls, off);
        if (lane == 0) su.comb.red[4 + wave] = ls;
        __syncthreads();
        float S = su.comb.red[4] + su.comb.red[5] + su.comb.red[6] + su.comb.red[7];
        out[tid] = e0 / S;
        out[tid + 256] = e1 / S;
    }
}

// ======================= launch =======================

extern "C" void kernel_launch(void* const* d_in, const int* in_sizes, int n_in,
                              void* d_out, int out_size, void* d_ws, size_t ws_size,
                              hipStream_t stream)
{
    const float* x      = (const float*)d_in[0];
    const float* W_ih   = (const float*)d_in[1];
    const float* W_hh   = (const float*)d_in[2];
    const float* b_ih   = (const float*)d_in[3];
    const float* b_hh   = (const float*)d_in[4];
    const float* W_proj = (const float*)d_in[5];
    const float* b_proj = (const float*)d_in[6];
    float* out          = (float*)d_out;
    float* ws           = (float*)d_ws;
    int N = in_sizes[0] / D;

    // size grid from actual occupancy so the cooperative co-residency check passes
    int dev = 0;
    (void)hipGetDevice(&dev);
    int cus = 256;
    (void)hipDeviceGetAttribute(&cus, hipDeviceAttributeMultiprocessorCount, dev);
    int maxb = 0;
    if (hipOccupancyMaxActiveBlocksPerMultiprocessor(&maxb, (const void*)s2s_kernel,
                                                     256, 0) != hipSuccess || maxb < 1)
        maxb = 1;
    long long Gll = (long long)cus * maxb;
    int G = (Gll > 512) ? 512 : (int)Gll;
    if (G < 8) G = 8;

    void* args[] = { (void*)&x, (void*)&W_ih, (void*)&W_hh, (void*)&b_ih,
                     (void*)&b_hh, (void*)&W_proj, (void*)&b_proj,
                     (void*)&out, (void*)&ws, (void*)&N };
    hipError_t e = hipLaunchCooperativeKernel((void*)s2s_kernel, dim3(G), dim3(256),
                                              args, 0, stream);
    if (e != hipSuccess) {
        (void)hipGetLastError();   // clear sticky error, use proven multi-kernel path
        float* hbuf   = ws + WS_HBUF;
        float* c      = ws + WS_C;
        float* ctx    = ws + WS_CTX;
        float* ctxs   = ws + WS_CTXS;
        float* logits = ws + WS_LOGITS;
        float* pm     = ws + WS_PM;
        float* ps     = ws + WS_PS;
        float* pv     = ws + WS_PV;
        const int B1 = MAXB1;

        hipMemsetAsync(d_ws, 0, 1536 * sizeof(float), stream);
        for (int t = 0; t < STEPS; ++t) {
            float* h_in  = hbuf + ((t & 1) << 9);
            float* h_out = hbuf + (((t + 1) & 1) << 9);
            attn_kernel<<<B1, 256, 0, stream>>>(x, h_in, pm, ps, pv, N);
            combine_kernel<<<8, 256, 0, stream>>>(pm, ps, pv, ctx, ctxs + t * D, B1);
            lstm_kernel<<<512, 256, 0, stream>>>(W_ih, W_hh, b_ih, b_hh, ctx, h_in, h_out, c);
        }
        proj_kernel<<<128, 256, 0, stream>>>(W_proj, b_proj, ctxs, logits);
        softmax512_kernel<<<1, 512, 0, stream>>>(logits, (float*)d_out);
    }
}

// Round 5
// 1449.574 us; speedup vs baseline: 1.1786x; 1.1786x over previous
//
#include <hip/hip_runtime.h>
#include <math.h>

#define D 512
#define STEPS 6
#define MAXG 1024

// ws float layout: bar[32 (u32)] | hbuf[1024] | c[512] | ctx[512] | ctxs[3072]
//                  | logits[512] | pm[1024] | ps[1024] | pv[1024*512]
#define WS_BAR    0
#define WS_HBUF   32
#define WS_C      1056
#define WS_CTX    1568
#define WS_CTXS   2080
#define WS_LOGITS 5152
#define WS_PM     5664
#define WS_PS     6688
#define WS_PV     7712

__device__ __forceinline__ float wave_reduce_sum(float v) {
#pragma unroll
    for (int off = 32; off > 0; off >>= 1) v += __shfl_xor(v, off);
    return v;
}

__device__ __forceinline__ float dot8(const float4& a, const float4& b,
                                      const float4& ha, const float4& hb) {
    return a.x*ha.x + a.y*ha.y + a.z*ha.z + a.w*ha.w
         + b.x*hb.x + b.y*hb.y + b.z*hb.z + b.w*hb.w;
}

// branch-free online softmax update (no divergent rescale, pipelines cleanly)
#define ONLINE_BF(dv, av, bv) do {                                       \
    float nm_ = fmaxf(m, (dv));                                          \
    float sc_ = __expf(m - nm_);     /* == 1.0 when max unchanged */     \
    float w_  = __expf((dv) - nm_);                                      \
    m = nm_;                                                             \
    s = s * sc_ + w_;                                                    \
    va.x = va.x*sc_ + w_*(av).x; va.y = va.y*sc_ + w_*(av).y;            \
    va.z = va.z*sc_ + w_*(av).z; va.w = va.w*sc_ + w_*(av).w;            \
    vb.x = vb.x*sc_ + w_*(bv).x; vb.y = vb.y*sc_ + w_*(bv).y;            \
    vb.z = vb.z*sc_ + w_*(bv).z; vb.w = vb.w*sc_ + w_*(bv).w;            \
} while (0)

// Hand-rolled grid barrier: one fresh counter per use (no sense reversal).
// Thread 0 arrives + spins with s_sleep backoff; rest of block parks at
// s_barrier. Device-scope fences around the atomic give release/acquire
// across XCD L2s (fence by one thread suffices: caches are CU/XCD-shared).
__device__ __forceinline__ void gbar(unsigned* cnt, unsigned NB) {
    __syncthreads();                       // drain block stores (vmcnt 0)
    if (threadIdx.x == 0) {
        __threadfence();                   // device-scope release
        atomicAdd(cnt, 1u);
        int spins = 0;
        while (__hip_atomic_load(cnt, __ATOMIC_RELAXED,
                                 __HIP_MEMORY_SCOPE_AGENT) < NB) {
            __builtin_amdgcn_s_sleep(2);
            if (++spins > (1 << 22)) break;   // bailout: never hang the harness
        }
        __threadfence();                   // device-scope acquire
    }
    __syncthreads();
}

struct SharedU {
    union {
        struct { float h_s[D]; float red_v[4][D]; float red_ms[8]; } attn;
        struct { float sm[MAXG]; float red[8]; float pr[4][64]; } comb;
        struct { float inp[2 * D]; float gate[4]; } lstm;
        struct { float cc[STEPS * D]; } proj;
    };
};

__global__ __launch_bounds__(256, 4) void s2s_kernel(
    const float* __restrict__ x,
    const float* __restrict__ W_ih, const float* __restrict__ W_hh,
    const float* __restrict__ b_ih, const float* __restrict__ b_hh,
    const float* __restrict__ W_proj, const float* __restrict__ b_proj,
    float* __restrict__ out, float* __restrict__ ws, int N)
{
    __shared__ SharedU su;

    unsigned* bar  = (unsigned*)(ws + WS_BAR);
    float* hbuf    = ws + WS_HBUF;
    float* c       = ws + WS_C;
    float* ctx     = ws + WS_CTX;
    float* ctxs    = ws + WS_CTXS;
    float* logits  = ws + WS_LOGITS;
    float* pm      = ws + WS_PM;
    float* ps      = ws + WS_PS;
    float* pv      = ws + WS_PV;

    const int tid = threadIdx.x, lane = tid & 63, wave = tid >> 6;
    const int bid = blockIdx.x;
    const unsigned NB = gridDim.x;       // <= 1024, co-resident by construction
    const int nw = (int)NB << 2;         // total waves
    int bslot = 0;

    for (int t = 0; t < STEPS; ++t) {
        float* h_in  = hbuf + ((t & 1) << 9);
        float* h_out = hbuf + (((t + 1) & 1) << 9);

        // ---- phase 1: online-softmax attention partials (streaming x) ----
        {
            for (int i = tid; i < D; i += 256) su.attn.h_s[i] = h_in[i];
            __syncthreads();
            const float4 ha = ((const float4*)su.attn.h_s)[lane];
            const float4 hb = ((const float4*)su.attn.h_s)[64 + lane];

            float m = -1e30f, s = 0.f;
            float4 va = make_float4(0.f, 0.f, 0.f, 0.f);
            float4 vb = make_float4(0.f, 0.f, 0.f, 0.f);

            int i = (bid << 2) + wave;
            const int limit4 = N - 3 * nw;
            for (; i < limit4; i += (nw << 2)) {
                const float4* x0 = (const float4*)(x + (size_t)i * D);
                const float4* x1 = (const float4*)(x + (size_t)(i + nw) * D);
                const float4* x2 = (const float4*)(x + (size_t)(i + 2 * nw) * D);
                const float4* x3 = (const float4*)(x + (size_t)(i + 3 * nw) * D);
                float4 a0 = x0[lane], b0 = x0[64 + lane];
                float4 a1 = x1[lane], b1 = x1[64 + lane];
                float4 a2 = x2[lane], b2 = x2[64 + lane];
                float4 a3 = x3[lane], b3 = x3[64 + lane];
                float d0 = dot8(a0, b0, ha, hb);
                float d1 = dot8(a1, b1, ha, hb);
                float d2 = dot8(a2, b2, ha, hb);
                float d3 = dot8(a3, b3, ha, hb);
#pragma unroll
                for (int off = 32; off > 0; off >>= 1) {
                    d0 += __shfl_xor(d0, off);
                    d1 += __shfl_xor(d1, off);
                    d2 += __shfl_xor(d2, off);
                    d3 += __shfl_xor(d3, off);
                }
                ONLINE_BF(d0, a0, b0);
                ONLINE_BF(d1, a1, b1);
                ONLINE_BF(d2, a2, b2);
                ONLINE_BF(d3, a3, b3);
            }
            for (; i < N; i += nw) {
                const float4* x0 = (const float4*)(x + (size_t)i * D);
                float4 a0 = x0[lane], b0 = x0[64 + lane];
                float d0 = dot8(a0, b0, ha, hb);
                d0 = wave_reduce_sum(d0);
                ONLINE_BF(d0, a0, b0);
            }

            ((float4*)su.attn.red_v[wave])[lane] = va;
            ((float4*)su.attn.red_v[wave])[64 + lane] = vb;
            if (lane == 0) { su.attn.red_ms[wave] = m; su.attn.red_ms[4 + wave] = s; }
            __syncthreads();

            float m0 = su.attn.red_ms[0], m1 = su.attn.red_ms[1];
            float m2 = su.attn.red_ms[2], m3 = su.attn.red_ms[3];
            float bm = fmaxf(fmaxf(m0, m1), fmaxf(m2, m3));
            float sc0 = __expf(m0 - bm), sc1 = __expf(m1 - bm);
            float sc2 = __expf(m2 - bm), sc3 = __expf(m3 - bm);
            if (tid == 0) {
                pm[bid] = bm;
                ps[bid] = su.attn.red_ms[4]*sc0 + su.attn.red_ms[5]*sc1
                        + su.attn.red_ms[6]*sc2 + su.attn.red_ms[7]*sc3;
            }
            float v0 = su.attn.red_v[0][tid]*sc0 + su.attn.red_v[1][tid]*sc1
                     + su.attn.red_v[2][tid]*sc2 + su.attn.red_v[3][tid]*sc3;
            float v1 = su.attn.red_v[0][tid+256]*sc0 + su.attn.red_v[1][tid+256]*sc1
                     + su.attn.red_v[2][tid+256]*sc2 + su.attn.red_v[3][tid+256]*sc3;
            pv[(size_t)bid * D + tid] = v0;
            pv[(size_t)bid * D + tid + 256] = v1;
        }
        gbar(&bar[bslot++], NB);

        // ---- phase 2: combine NB partials -> ctx ----
        if (bid < 8) {
            float lm = -1e30f;
            for (int b = tid; b < (int)NB; b += 256) lm = fmaxf(lm, pm[b]);
#pragma unroll
            for (int off = 32; off > 0; off >>= 1) lm = fmaxf(lm, __shfl_xor(lm, off));
            if (lane == 0) su.comb.red[wave] = lm;
            __syncthreads();
            float M = fmaxf(fmaxf(su.comb.red[0], su.comb.red[1]),
                            fmaxf(su.comb.red[2], su.comb.red[3]));

            float lS = 0.f;
            for (int b = tid; b < (int)NB; b += 256) {
                float e = __expf(pm[b] - M);
                su.comb.sm[b] = e;
                lS += ps[b] * e;
            }
#pragma unroll
            for (int off = 32; off > 0; off >>= 1) lS += __shfl_xor(lS, off);
            if (lane == 0) su.comb.red[4 + wave] = lS;
            __syncthreads();
            float S = su.comb.red[4] + su.comb.red[5] + su.comb.red[6] + su.comb.red[7];

            const int d = (bid << 6) + lane;
            float acc = 0.f;
            for (int b = wave; b < (int)NB; b += 4)
                acc += pv[(size_t)b * D + d] * su.comb.sm[b];
            su.comb.pr[wave][lane] = acc;
            __syncthreads();
            if (tid < 64) {
                float v = (su.comb.pr[0][lane] + su.comb.pr[1][lane]
                         + su.comb.pr[2][lane] + su.comb.pr[3][lane]) / S;
                ctx[d] = v;
                ctxs[t * D + d] = v;
            }
        }
        gbar(&bar[bslot++], NB);

        // ---- phase 3: LSTM cell ----
        {
            for (int i = tid; i < D; i += 256) {
                su.lstm.inp[i] = ctx[i];
                su.lstm.inp[D + i] = h_in[i];
            }
            __syncthreads();

            for (int j = bid; j < D; j += (int)NB) {
                const int row = (wave << 9) + j;   // gate order i,f,g,o
                const float4* wr = (const float4*)(W_ih + (size_t)row * (2 * D));
                float dot = 0.f;
#pragma unroll
                for (int q = 0; q < 4; ++q) {
                    float4 w4 = wr[lane + (q << 6)];
                    float4 i4 = ((const float4*)su.lstm.inp)[lane + (q << 6)];
                    dot += w4.x*i4.x + w4.y*i4.y + w4.z*i4.z + w4.w*i4.w;
                }
                const float4* wr2 = (const float4*)(W_hh + (size_t)row * D);
#pragma unroll
                for (int q = 0; q < 2; ++q) {
                    float4 w4 = wr2[lane + (q << 6)];
                    float4 i4 = ((const float4*)(su.lstm.inp + D))[lane + (q << 6)];
                    dot += w4.x*i4.x + w4.y*i4.y + w4.z*i4.z + w4.w*i4.w;
                }
                dot = wave_reduce_sum(dot);
                if (lane == 0) su.lstm.gate[wave] = dot + b_ih[row] + b_hh[row];
                __syncthreads();
                if (tid == 0) {
                    float ig = 1.f / (1.f + __expf(-su.lstm.gate[0]));
                    float fg = 1.f / (1.f + __expf(-su.lstm.gate[1]));
                    float gg = tanhf(su.lstm.gate[2]);
                    float og = 1.f / (1.f + __expf(-su.lstm.gate[3]));
                    float cn = fg * c[j] + ig * gg;
                    c[j] = cn;
                    h_out[j] = og * tanhf(cn);
                }
                __syncthreads();
            }
        }
        gbar(&bar[bslot++], NB);
    }

    // ---- projection ----
    {
        for (int i = tid; i < STEPS * D; i += 256) su.proj.cc[i] = ctxs[i];
        __syncthreads();
        for (int rg = bid; rg < 128; rg += (int)NB) {
            const int row = (rg << 2) + wave;
            const float4* wr = (const float4*)(W_proj + (size_t)row * (STEPS * D));
            float dot = 0.f;
#pragma unroll
            for (int q = 0; q < 12; ++q) {
                float4 w4 = wr[lane + (q << 6)];
                float4 i4 = ((const float4*)su.proj.cc)[lane + (q << 6)];
                dot += w4.x*i4.x + w4.y*i4.y + w4.z*i4.z + w4.w*i4.w;
            }
            dot = wave_reduce_sum(dot);
            if (lane == 0) logits[row] = dot + b_proj[row];
        }
    }
    gbar(&bar[bslot++], NB);

    // ---- final softmax over 512 logits (block 0) ----
    if (bid == 0) {
        float v0 = logits[tid], v1 = logits[tid + 256];
        float m = fmaxf(v0, v1);
#pragma unroll
        for (int off = 32; off > 0; off >>= 1) m = fmaxf(m, __shfl_xor(m, off));
        if (lane == 0) su.comb.red[wave] = m;
        __syncthreads();
        m = fmaxf(fmaxf(su.comb.red[0], su.comb.red[1]),
                  fmaxf(su.comb.red[2], su.comb.red[3]));
        __syncthreads();
        float e0 = __expf(v0 - m), e1 = __expf(v1 - m);
        float ls = e0 + e1;
#pragma unroll
        for (int off = 32; off > 0; off >>= 1) ls += __shfl_xor(ls, off);
        if (lane == 0) su.comb.red[4 + wave] = ls;
        __syncthreads();
        float S = su.comb.red[4] + su.comb.red[5] + su.comb.red[6] + su.comb.red[7];
        out[tid] = e0 / S;
        out[tid + 256] = e1 / S;
    }
}

extern "C" void kernel_launch(void* const* d_in, const int* in_sizes, int n_in,
                              void* d_out, int out_size, void* d_ws, size_t ws_size,
                              hipStream_t stream)
{
    const float* x      = (const float*)d_in[0];
    const float* W_ih   = (const float*)d_in[1];
    const float* W_hh   = (const float*)d_in[2];
    const float* b_ih   = (const float*)d_in[3];
    const float* b_hh   = (const float*)d_in[4];
    const float* W_proj = (const float*)d_in[5];
    const float* b_proj = (const float*)d_in[6];
    float* out          = (float*)d_out;
    float* ws           = (float*)d_ws;
    int N = in_sizes[0] / D;

    // grid sized from real occupancy so ALL blocks are co-resident (barrier safety)
    int dev = 0;
    (void)hipGetDevice(&dev);
    int cus = 256;
    (void)hipDeviceGetAttribute(&cus, hipDeviceAttributeMultiprocessorCount, dev);
    int maxb = 0;
    if (hipOccupancyMaxActiveBlocksPerMultiprocessor(&maxb, (const void*)s2s_kernel,
                                                     256, 0) != hipSuccess || maxb < 1)
        maxb = 1;
    long long Gll = (long long)cus * maxb;
    int G = (Gll > MAXG) ? MAXG : (int)Gll;
    if (G < 8) G = 8;

    // zero barrier counters (32 u32) + h double-buffer (1024 f) + c (512 f)
    hipMemsetAsync(d_ws, 0, (32 + 1024 + 512) * sizeof(float), stream);

    s2s_kernel<<<dim3(G), dim3(256), 0, stream>>>(x, W_ih, W_hh, b_ih, b_hh,
                                                  W_proj, b_proj, out, ws, N);
}